// Round 19
// baseline (378.331 us; speedup 1.0000x reference)
//
#include <hip/hip_runtime.h>
#include <hip/hip_fp16.h>
#include <cmath>

static inline int cdiv(long a, int b){ return (int)((a + b - 1) / b); }

__device__ __forceinline__ float lrelu(float x){ return fmaxf(x, 0.2f * x); }
__device__ __forceinline__ float elu1(float x){ return x > 0.f ? x : expm1f(x); }
__device__ __forceinline__ float fexp2(float x){ return exp2f(x); }   // v_exp_f32
__device__ __forceinline__ float sel4(float4 v, int h){
  float ab = (h & 1) ? v.y : v.x;
  float cd = (h & 1) ? v.w : v.z;
  return (h & 2) ? cd : ab;
}
__device__ __forceinline__ float dot8(float4 a, float4 b, float4 u, float4 v){
  float p = a.x * u.x;
  p = fmaf(a.y, u.y, p); p = fmaf(a.z, u.z, p); p = fmaf(a.w, u.w, p);
  p = fmaf(b.x, v.x, p); p = fmaf(b.y, v.y, p); p = fmaf(b.z, v.z, p);
  return fmaf(b.w, v.w, p);
}

// NW-wave block exclusive scan, 2 barriers. s_wsum: int[NW]; s_wsum[NW-1]=total.
template<int NW>
__device__ __forceinline__ int block_exscan(int v, int* s_wsum, int t){
  int lane = t & 63, w = t >> 6;
  int x = v;
  #pragma unroll
  for (int off = 1; off < 64; off <<= 1){
    int u = __shfl_up(x, off, 64);
    if (lane >= off) x += u;
  }
  if (lane == 63) s_wsum[w] = x;
  __syncthreads();
  if (w == 0 && lane < NW){
    int y = s_wsum[lane];
    #pragma unroll
    for (int off = 1; off < NW; off <<= 1){
      int u = __shfl_up(y, off, 64);
      if (lane >= off) y += u;
    }
    s_wsum[lane] = y;
  }
  __syncthreads();
  int wbase = w ? s_wsum[w - 1] : 0;
  return wbase + x - v;
}

#define W_SHIFT 7                 // 128 nodes per bucket
#define BUCKET_N (1 << W_SHIFT)
#define NBMAX   1024              // >= number of buckets (782)
#define NCHUNKS 2048              // chunks (2 per col_scan thread)
#define CH_MAX  1600              // max edges per chunk (E/NCHUNKS = 1563)
#define MS_THREADS 512            // multisplit block: 8 waves, 4 blocks/CU
#define BS_THREADS 1024

// staged record: {src, dst(full), esc01(fp16x2), esc23(fp16x2)}; esc pre-scaled by log2e

// ---------------- CSR build (atomic-free scheduling) ----------------

__global__ __launch_bounds__(1024)
void hist_chunks_kernel(const int* __restrict__ ei, int E, int CH, int* __restrict__ hist2d){
  __shared__ int s_b[NBMAX];
  int t = threadIdx.x, chunk = blockIdx.x;
  s_b[t] = 0;
  __syncthreads();
  int lo = chunk * CH, hi = min(lo + CH, E);
  for (int e = lo + t; e < hi; e += 1024)
    atomicAdd(&s_b[ei[E + e] >> W_SHIFT], 1);
  __syncthreads();
  hist2d[(size_t)chunk * NBMAX + t] = s_b[t];
}

// per bucket: exclusive prefix over 2048 chunks (2 per thread), total -> bcnt
__global__ __launch_bounds__(1024)
void col_scan_kernel(int* __restrict__ hist2d, int* __restrict__ bcnt){
  __shared__ int s_wsum[16];
  int b = blockIdx.x, t = threadIdx.x;
  size_t i0 = (size_t)(2 * t) * NBMAX + b;
  size_t i1 = (size_t)(2 * t + 1) * NBMAX + b;
  int v0 = hist2d[i0], v1 = hist2d[i1];
  int excl = block_exscan<16>(v0 + v1, s_wsum, t);
  hist2d[i0] = excl;
  hist2d[i1] = excl + v0;
  if (t == 0) bcnt[b] = s_wsum[15];
}

__global__ __launch_bounds__(1024)
void scan_buckets_kernel(const int* __restrict__ bcnt, int nb, int total,
                         int* __restrict__ bstart, int* __restrict__ row_start, int n){
  __shared__ int s_wsum[16];
  int t = threadIdx.x;
  int v = (t < nb) ? bcnt[t] : 0;
  int excl = block_exscan<16>(v, s_wsum, t);
  bstart[t] = excl;                       // for t >= nb, excl == total
  if (t == 0){ bstart[NBMAX] = total; row_start[n] = total; }
}

// wev scaled by log2e; avecs = scaled attention vecs:
// [as1s 0..31 | ad1s 32..63 | as2s 64..95 | ad2s 96..127 | as3s 128..131 | ad3s 132..135]
__global__ void prep_kernel(const float* __restrict__ We, const float* __restrict__ ae,
                            const float* __restrict__ as1, const float* __restrict__ ad1,
                            const float* __restrict__ as2, const float* __restrict__ ad2,
                            const float* __restrict__ as3, const float* __restrict__ ad3,
                            float* __restrict__ wev, float* __restrict__ avecs){
  const float L2E = 1.4426950408889634f;
  int i = threadIdx.x;
  if (i < 32){
    int d = i >> 2, h = i & 3;
    float acc = 0.f;
    #pragma unroll
    for (int c = 0; c < 8; ++c) acc = fmaf(We[d * 32 + h * 8 + c], ae[h * 8 + c], acc);
    wev[d * 4 + h] = acc * L2E;
    avecs[i]      = as1[i] * L2E;
    avecs[32 + i] = ad1[i] * L2E;
    avecs[64 + i] = as2[i] * L2E;
    avecs[96 + i] = ad2[i] * L2E;
  }
  if (i < 4){
    avecs[128 + i] = as3[i] * L2E;
    avecs[132 + i] = ad3[i] * L2E;
  }
}

// multisplit v5: 512-thread blocks, ~38 KB LDS -> 4 blocks/CU. Record sort in
// LDS (SoA 8B+8B), counts derived from plan (no histogram pass), dense copy-out.
__global__ __launch_bounds__(MS_THREADS)
void multisplit_kernel(const int* __restrict__ ei, int E, int CH,
                       const float* __restrict__ eattr, const float* __restrict__ wev,
                       const int* __restrict__ bstart, const int* __restrict__ prefix2d,
                       const int* __restrict__ bcnt, int4* __restrict__ staged){
  __shared__ int2 s_ra[CH_MAX];        // {src, dst}      12.8 KB
  __shared__ int2 s_rb[CH_MAX];        // {esc01, esc23}  12.8 KB
  __shared__ int s_fill[NBMAX];
  __shared__ int s_lbase[NBMAX];
  __shared__ int s_shift[NBMAX];
  __shared__ float s_wev[32];
  __shared__ int s_wsum[8];
  int t = threadIdx.x, chunk = blockIdx.x;
  if (t < 32) s_wev[t] = wev[t];
  int b0i = 2 * t, b1i = 2 * t + 1;    // each thread owns 2 buckets
  int pme0 = prefix2d[(size_t)chunk * NBMAX + b0i];
  int pme1 = prefix2d[(size_t)chunk * NBMAX + b1i];
  int pnx0, pnx1;
  if (chunk + 1 < NCHUNKS){
    pnx0 = prefix2d[(size_t)(chunk + 1) * NBMAX + b0i];
    pnx1 = prefix2d[(size_t)(chunk + 1) * NBMAX + b1i];
  } else {
    pnx0 = bcnt[b0i]; pnx1 = bcnt[b1i];
  }
  int c0 = pnx0 - pme0, c1 = pnx1 - pme1;
  int excl = block_exscan<8>(c0 + c1, s_wsum, t);   // includes 2 barriers
  s_lbase[b0i] = excl;
  s_lbase[b1i] = excl + c0;
  s_shift[b0i] = bstart[b0i] + pme0 - excl;
  s_shift[b1i] = bstart[b1i] + pme1 - (excl + c0);
  s_fill[b0i] = 0; s_fill[b1i] = 0;
  __syncthreads();
  int lo = chunk * CH, hi = min(lo + CH, E);
  int cnt = hi - lo;
  for (int e = lo + t; e < hi; e += MS_THREADS){
    int d = ei[E + e];
    int b = d >> W_SHIFT;
    const float4* ea = (const float4*)(eattr + (size_t)e * 8);
    float4 v0 = ea[0], v1 = ea[1];
    float av[8] = {v0.x, v0.y, v0.z, v0.w, v1.x, v1.y, v1.z, v1.w};
    float e0 = 0, e1 = 0, e2 = 0, e3 = 0;
    #pragma unroll
    for (int k = 0; k < 8; ++k){
      e0 = fmaf(av[k], s_wev[k * 4 + 0], e0);
      e1 = fmaf(av[k], s_wev[k * 4 + 1], e1);
      e2 = fmaf(av[k], s_wev[k * 4 + 2], e2);
      e3 = fmaf(av[k], s_wev[k * 4 + 3], e3);
    }
    __half2 h01 = __floats2half2_rn(e0, e1);
    __half2 h23 = __floats2half2_rn(e2, e3);
    int pos = s_lbase[b] + atomicAdd(&s_fill[b], 1);
    s_ra[pos] = make_int2(ei[e], d);
    s_rb[pos] = make_int2(__builtin_bit_cast(int, h01), __builtin_bit_cast(int, h23));
  }
  __syncthreads();
  // dense copy-out: consecutive threads -> mostly-consecutive global addresses
  for (int i = t; i < cnt; i += MS_THREADS){
    int2 a = s_ra[i];
    int2 b2 = s_rb[i];
    staged[s_shift[a.y >> W_SHIFT] + i] = make_int4(a.x, a.y, b2.x, b2.y);
  }
}

// per-bucket: counts -> row_start; permute staged to final CSR (srcs 4B + escp 8B);
// then 8-lane-per-node esc row sums from the L2-hot escp window -> selfesc.
__global__ __launch_bounds__(BS_THREADS)
void bucket_scatter_kernel(const int* __restrict__ bstart, const int4* __restrict__ staged,
                           int n, int* __restrict__ row_start, int* __restrict__ srcs,
                           uint2* __restrict__ escp, float4* __restrict__ selfesc){
  __shared__ int s_cnt[BUCKET_N];
  __shared__ int s_cur[BUCKET_N];
  __shared__ int s_start[BUCKET_N];
  __shared__ int s_wsum[2];
  int b = blockIdx.x, t = threadIdx.x;
  int node0 = b << W_SHIFT;
  if (t < BUCKET_N) s_cnt[t] = 0;
  __syncthreads();
  int lo = bstart[b], hi = bstart[b + 1];
  for (int i = lo + t; i < hi; i += BS_THREADS)
    atomicAdd(&s_cnt[staged[i].y & (BUCKET_N - 1)], 1);
  __syncthreads();
  int lane = t & 63, w = t >> 6;
  if (w < 2){
    int v = s_cnt[t];
    int x = v;
    #pragma unroll
    for (int off = 1; off < 64; off <<= 1){
      int u = __shfl_up(x, off, 64);
      if (lane >= off) x += u;
    }
    if (lane == 63) s_wsum[w] = x;
    s_cur[t] = x - v;
  }
  __syncthreads();
  if (t < BUCKET_N){
    int excl = s_cur[t] + (w ? s_wsum[0] : 0);
    int nd = node0 + t;
    if (nd <= n) row_start[nd] = lo + excl;
    s_start[t] = lo + excl;
    s_cur[t] = lo + excl;
  }
  __syncthreads();
  for (int i = lo + t; i < hi; i += BS_THREADS){
    int4 r = staged[i];
    int pos = atomicAdd(&s_cur[r.y & (BUCKET_N - 1)], 1);
    srcs[pos] = r.x;
    escp[pos] = make_uint2((unsigned)r.z, (unsigned)r.w);
  }
  __syncthreads();
  int nl = t >> 3, sub = t & 7;
  int nd2 = node0 + nl;
  if (nd2 >= n) return;
  int r0 = s_start[nl], r1 = s_start[nl] + s_cnt[nl];
  float e0 = 0, e1 = 0, e2 = 0, e3 = 0;
  for (int k = r0 + sub; k < r1; k += 8){
    uint2 u = escp[k];
    float2 f01 = __half22float2(__builtin_bit_cast(__half2, u.x));
    float2 f23 = __half22float2(__builtin_bit_cast(__half2, u.y));
    e0 += f01.x; e1 += f01.y; e2 += f23.x; e3 += f23.y;
  }
  #pragma unroll
  for (int off = 1; off < 8; off <<= 1){
    e0 += __shfl_xor(e0, off, 64); e1 += __shfl_xor(e1, off, 64);
    e2 += __shfl_xor(e2, off, 64); e3 += __shfl_xor(e3, off, 64);
  }
  if (sub == 0){
    float inv = 1.f / fmaxf((float)s_cnt[nl], 1.f);
    selfesc[nd2] = make_float4(e0 * inv, e1 * inv, e2 * inv, e3 * inv);
  }
}

// ---------------- register-tiled node transform (pure GEMM) ----------------
template<int K>
__global__ __launch_bounds__(256)
void gemm_tiled(const float* __restrict__ A, const float* __restrict__ W,
                float* __restrict__ out, int n){
  constexpr int KH = (K > 64) ? 64 : K;
  constexpr int K4 = KH / 4;
  __shared__ float s_AT[KH * 128];
  __shared__ float s_W[K * 32];
  int t = threadIdx.x;
  for (int i = t; i < K * 32; i += 256) s_W[i] = W[i];
  int n0 = blockIdx.x * 128;
  int nrows = min(128, n - n0);
  int rg = t >> 3, q = t & 7;
  float4 acc[4] = {{0,0,0,0},{0,0,0,0},{0,0,0,0},{0,0,0,0}};

  for (int k0 = 0; k0 < K; k0 += KH){
    __syncthreads();
    #pragma unroll
    for (int it = 0; it < 128 * K4 / 256; ++it){
      int idx = t + it * 256;
      int row = idx & 127, k4 = idx >> 7;
      if (row < nrows){
        float4 v = *(const float4*)(A + (size_t)(n0 + row) * K + k0 + 4 * k4);
        s_AT[(4 * k4 + 0) * 128 + row] = v.x;
        s_AT[(4 * k4 + 1) * 128 + row] = v.y;
        s_AT[(4 * k4 + 2) * 128 + row] = v.z;
        s_AT[(4 * k4 + 3) * 128 + row] = v.w;
      }
    }
    __syncthreads();
    #pragma unroll 4
    for (int k = 0; k < KH; ++k){
      float4 a4 = *(const float4*)(s_AT + k * 128 + 4 * rg);
      float4 w4 = *(const float4*)(s_W + (k0 + k) * 32 + 4 * q);
      acc[0].x = fmaf(a4.x, w4.x, acc[0].x); acc[0].y = fmaf(a4.x, w4.y, acc[0].y);
      acc[0].z = fmaf(a4.x, w4.z, acc[0].z); acc[0].w = fmaf(a4.x, w4.w, acc[0].w);
      acc[1].x = fmaf(a4.y, w4.x, acc[1].x); acc[1].y = fmaf(a4.y, w4.y, acc[1].y);
      acc[1].z = fmaf(a4.y, w4.z, acc[1].z); acc[1].w = fmaf(a4.y, w4.w, acc[1].w);
      acc[2].x = fmaf(a4.z, w4.x, acc[2].x); acc[2].y = fmaf(a4.z, w4.y, acc[2].y);
      acc[2].z = fmaf(a4.z, w4.z, acc[2].z); acc[2].w = fmaf(a4.z, w4.w, acc[2].w);
      acc[3].x = fmaf(a4.w, w4.x, acc[3].x); acc[3].y = fmaf(a4.w, w4.y, acc[3].y);
      acc[3].z = fmaf(a4.w, w4.z, acc[3].z); acc[3].w = fmaf(a4.w, w4.w, acc[3].w);
    }
  }
  #pragma unroll
  for (int i = 0; i < 4; ++i){
    int row = n0 + 4 * rg + i;
    if ((4 * rg + i) < nrows) ((float4*)out)[(size_t)row * 8 + q] = acc[i];
  }
}

// ---------------- one-phase CSR gather: 4 lanes/edge, srcs/escp prefetch ----------------
template<int MODE, bool EDGE>
__global__ void gather_kernel(const int* __restrict__ row_start, const int* __restrict__ srcs,
                              const uint2* __restrict__ escp, const float4* __restrict__ selfesc,
                              const float* __restrict__ xh, const float* __restrict__ avq,
                              const float* __restrict__ bias, float* __restrict__ out, int n,
                              const float* __restrict__ W3p, float* __restrict__ xh3){
  int wv = threadIdx.x >> 6, lane = threadIdx.x & 63;
  int node = blockIdx.x * 4 + wv;

  if constexpr (MODE == 2){
    if (node >= n) return;
    int rs = row_start[node], deg = row_start[node + 1] - rs;
    float4 a3s = *(const float4*)avq;
    float4 a3d = *(const float4*)(avq + 4);
    float4 xvn = ((const float4*)xh)[node];
    float4 sdn = {xvn.x * a3d.x, xvn.y * a3d.y, xvn.z * a3d.z, xvn.w * a3d.w};
    float4 acc = {0,0,0,0}, dsum = {0,0,0,0};
    for (int k = lane; k < deg; k += 64){
      int s = srcs[rs + k];
      float4 xv = ((const float4*)xh)[s];
      float4 w;
      w.x = fexp2(lrelu(fmaf(xv.x, a3s.x, sdn.x)));
      w.y = fexp2(lrelu(fmaf(xv.y, a3s.y, sdn.y)));
      w.z = fexp2(lrelu(fmaf(xv.z, a3s.z, sdn.z)));
      w.w = fexp2(lrelu(fmaf(xv.w, a3s.w, sdn.w)));
      dsum.x += w.x; dsum.y += w.y; dsum.z += w.z; dsum.w += w.w;
      acc.x = fmaf(w.x, xv.x, acc.x); acc.y = fmaf(w.y, xv.y, acc.y);
      acc.z = fmaf(w.z, xv.z, acc.z); acc.w = fmaf(w.w, xv.w, acc.w);
    }
    #pragma unroll
    for (int off = 1; off < 64; off <<= 1){
      acc.x += __shfl_xor(acc.x, off, 64); acc.y += __shfl_xor(acc.y, off, 64);
      acc.z += __shfl_xor(acc.z, off, 64); acc.w += __shfl_xor(acc.w, off, 64);
      dsum.x += __shfl_xor(dsum.x, off, 64); dsum.y += __shfl_xor(dsum.y, off, 64);
      dsum.z += __shfl_xor(dsum.z, off, 64); dsum.w += __shfl_xor(dsum.w, off, 64);
    }
    if (lane == 0){
      float4 wsf;
      wsf.x = fexp2(lrelu(fmaf(xvn.x, a3s.x, sdn.x)));
      wsf.y = fexp2(lrelu(fmaf(xvn.y, a3s.y, sdn.y)));
      wsf.z = fexp2(lrelu(fmaf(xvn.z, a3s.z, sdn.z)));
      wsf.w = fexp2(lrelu(fmaf(xvn.w, a3s.w, sdn.w)));
      float v = (acc.x + wsf.x * xvn.x) / (dsum.x + wsf.x + 1e-16f)
              + (acc.y + wsf.y * xvn.y) / (dsum.y + wsf.y + 1e-16f)
              + (acc.z + wsf.z * xvn.z) / (dsum.z + wsf.z + 1e-16f)
              + (acc.w + wsf.w * xvn.w) / (dsum.w + wsf.w + 1e-16f);
      out[node] = 0.25f * v + bias[0];
    }
    return;
  } else {
  __shared__ float s_w3[32];
  if constexpr (MODE == 1){
    if (threadIdx.x < 32) s_w3[threadIdx.x] = W3p[threadIdx.x];
    __syncthreads();
  }
  if (node >= n) return;
  int rs = row_start[node], deg = row_start[node + 1] - rs;
  int h = lane & 3, sg = lane >> 2;          // head, edge slot (16 edges/iter)
  const float4* xh4 = (const float4*)xh;
  float4 as0 = ((const float4*)avq)[2 * h];
  float4 as1v = ((const float4*)avq)[2 * h + 1];
  float4 ad0 = ((const float4*)(avq + 32))[2 * h];
  float4 ad1v = ((const float4*)(avq + 32))[2 * h + 1];
  float4 xn0 = xh4[(size_t)node * 8 + 2 * h];
  float4 xn1 = xh4[(size_t)node * 8 + 2 * h + 1];
  float sdh = dot8(xn0, xn1, ad0, ad1v);
  float4 acc0 = {0,0,0,0}, acc1 = {0,0,0,0};
  float dacc = 0.f;
  const int* sp = srcs + rs;

  int k = sg;
  int s_cur = (k < deg) ? sp[k] : -1;
  uint2 u_cur = (EDGE && k < deg) ? escp[rs + k] : make_uint2(0u, 0u);
  for (int base = 0; base < deg; base += 16){
    int k2 = base + 16 + sg;
    int s_nxt = (k2 < deg) ? sp[k2] : -1;
    uint2 u_nxt = (EDGE && k2 < deg) ? escp[rs + k2] : make_uint2(0u, 0u);
    if (s_cur >= 0){
      float4 xv0 = xh4[(size_t)s_cur * 8 + 2 * h];
      float4 xv1 = xh4[(size_t)s_cur * 8 + 2 * h + 1];
      float a = dot8(xv0, xv1, as0, as1v) + sdh;
      if constexpr (EDGE){
        float2 f01 = __half22float2(__builtin_bit_cast(__half2, u_cur.x));
        float2 f23 = __half22float2(__builtin_bit_cast(__half2, u_cur.y));
        a += (h == 0) ? f01.x : (h == 1) ? f01.y : (h == 2) ? f23.x : f23.y;
      }
      float w = fexp2(lrelu(a));
      dacc += w;
      acc0.x = fmaf(w, xv0.x, acc0.x); acc0.y = fmaf(w, xv0.y, acc0.y);
      acc0.z = fmaf(w, xv0.z, acc0.z); acc0.w = fmaf(w, xv0.w, acc0.w);
      acc1.x = fmaf(w, xv1.x, acc1.x); acc1.y = fmaf(w, xv1.y, acc1.y);
      acc1.z = fmaf(w, xv1.z, acc1.z); acc1.w = fmaf(w, xv1.w, acc1.w);
    }
    s_cur = s_nxt;
    u_cur = u_nxt;
  }

  #pragma unroll
  for (int off = 4; off < 64; off <<= 1){
    acc0.x += __shfl_xor(acc0.x, off, 64); acc0.y += __shfl_xor(acc0.y, off, 64);
    acc0.z += __shfl_xor(acc0.z, off, 64); acc0.w += __shfl_xor(acc0.w, off, 64);
    acc1.x += __shfl_xor(acc1.x, off, 64); acc1.y += __shfl_xor(acc1.y, off, 64);
    acc1.z += __shfl_xor(acc1.z, off, 64); acc1.w += __shfl_xor(acc1.w, off, 64);
    dacc   += __shfl_xor(dacc,   off, 64);
  }
  float a_self = dot8(xn0, xn1, as0, as1v) + sdh;
  if constexpr (EDGE) a_self += sel4(selfesc[node], h);
  float wsel = fexp2(lrelu(a_self));
  acc0.x = fmaf(wsel, xn0.x, acc0.x); acc0.y = fmaf(wsel, xn0.y, acc0.y);
  acc0.z = fmaf(wsel, xn0.z, acc0.z); acc0.w = fmaf(wsel, xn0.w, acc0.w);
  acc1.x = fmaf(wsel, xn1.x, acc1.x); acc1.y = fmaf(wsel, xn1.y, acc1.y);
  acc1.z = fmaf(wsel, xn1.z, acc1.z); acc1.w = fmaf(wsel, xn1.w, acc1.w);
  dacc += wsel;
  float rin = 1.f / (dacc + 1e-16f);
  float4 v0 = {acc0.x * rin, acc0.y * rin, acc0.z * rin, acc0.w * rin};
  float4 v1 = {acc1.x * rin, acc1.y * rin, acc1.z * rin, acc1.w * rin};

  if constexpr (MODE == 0){
    if (sg == 0){
      float4 ba = ((const float4*)bias)[2 * h];
      float4 bb = ((const float4*)bias)[2 * h + 1];
      v0.x = elu1(v0.x + ba.x); v0.y = elu1(v0.y + ba.y);
      v0.z = elu1(v0.z + ba.z); v0.w = elu1(v0.w + ba.w);
      v1.x = elu1(v1.x + bb.x); v1.y = elu1(v1.y + bb.y);
      v1.z = elu1(v1.z + bb.z); v1.w = elu1(v1.w + bb.w);
      ((float4*)out)[(size_t)node * 8 + 2 * h] = v0;
      ((float4*)out)[(size_t)node * 8 + 2 * h + 1] = v1;
    }
  } else {
    #pragma unroll
    for (int off = 1; off < 4; off <<= 1){
      v0.x += __shfl_xor(v0.x, off, 64); v0.y += __shfl_xor(v0.y, off, 64);
      v0.z += __shfl_xor(v0.z, off, 64); v0.w += __shfl_xor(v0.w, off, 64);
      v1.x += __shfl_xor(v1.x, off, 64); v1.y += __shfl_xor(v1.y, off, 64);
      v1.z += __shfl_xor(v1.z, off, 64); v1.w += __shfl_xor(v1.w, off, 64);
    }
    float4 ba = ((const float4*)bias)[0];
    float4 bb = ((const float4*)bias)[1];
    float h2v[8];
    h2v[0] = elu1(v0.x * 0.25f + ba.x); h2v[1] = elu1(v0.y * 0.25f + ba.y);
    h2v[2] = elu1(v0.z * 0.25f + ba.z); h2v[3] = elu1(v0.w * 0.25f + ba.w);
    h2v[4] = elu1(v1.x * 0.25f + bb.x); h2v[5] = elu1(v1.y * 0.25f + bb.y);
    h2v[6] = elu1(v1.z * 0.25f + bb.z); h2v[7] = elu1(v1.w * 0.25f + bb.w);
    if (sg == 0){
      float a = 0.f;
      #pragma unroll
      for (int kk = 0; kk < 8; ++kk) a = fmaf(h2v[kk], s_w3[kk * 4 + h], a);
      xh3[(size_t)node * 4 + h] = a;
    }
  }
  }
}

// ---------------- launcher ----------------

extern "C" void kernel_launch(void* const* d_in, const int* in_sizes, int n_in,
                              void* d_out, int out_size, void* d_ws, size_t ws_size,
                              hipStream_t stream){
  const float* x     = (const float*)d_in[0];
  const float* eattr = (const float*)d_in[1];
  const int*   ei    = (const int*)d_in[2];
  const float* W1  = (const float*)d_in[3];
  const float* as1 = (const float*)d_in[4];
  const float* ad1 = (const float*)d_in[5];
  const float* We1 = (const float*)d_in[6];
  const float* ae1 = (const float*)d_in[7];
  const float* b1  = (const float*)d_in[8];
  const float* W2  = (const float*)d_in[9];
  const float* as2 = (const float*)d_in[10];
  const float* ad2 = (const float*)d_in[11];
  const float* b2  = (const float*)d_in[12];
  const float* W3  = (const float*)d_in[13];
  const float* as3 = (const float*)d_in[14];
  const float* ad3 = (const float*)d_in[15];
  const float* b3  = (const float*)d_in[16];

  const int N = in_sizes[0] / 128;
  const int E = in_sizes[2] / 2;
  const int nb_buckets = (N + BUCKET_N - 1) >> W_SHIFT;   // 782 for N=100000
  const int CH = cdiv(E, NCHUNKS);                        // 1563 (<= CH_MAX)

  char* b0 = (char*)d_ws;
  int4* staged = (int4*)b0;                 // E*16; aliased by xh/h1 after CSR build
  float* fp = (float*)b0;
  float* xh = fp; fp += (size_t)N * 32;
  float* h1 = fp; fp += (size_t)N * 32;
  int*  srcs = (int*)(b0 + (size_t)E * 16);
  uint2* escp = (uint2*)(b0 + (size_t)E * 20);
  int* hist2d = (int*)(b0 + (size_t)E * 28);
  float4* selfesc = (float4*)(hist2d + (size_t)NCHUNKS * NBMAX);
  float* xh3 = (float*)(selfesc + N);
  int* ip = (int*)(xh3 + (size_t)N * 4);
  int* bcnt      = ip; ip += NBMAX;
  int* bstart    = ip; ip += NBMAX + 1;
  int* row_start = ip; ip += N + 1;
  float* wev   = (float*)ip;
  float* avecs = wev + 32;

  const int B = 256;

  // ---- CSR build: plan (no global atomics) -> LDS record-sort multisplit -> bucket scatter ----
  prep_kernel<<<1, 64, 0, stream>>>(We1, ae1, as1, ad1, as2, ad2, as3, ad3, wev, avecs);
  hist_chunks_kernel<<<NCHUNKS, 1024, 0, stream>>>(ei, E, CH, hist2d);
  col_scan_kernel<<<nb_buckets, 1024, 0, stream>>>(hist2d, bcnt);
  scan_buckets_kernel<<<1, 1024, 0, stream>>>(bcnt, nb_buckets, E, bstart, row_start, N);
  multisplit_kernel<<<NCHUNKS, MS_THREADS, 0, stream>>>(ei, E, CH, eattr, wev, bstart, hist2d, bcnt, staged);
  bucket_scatter_kernel<<<nb_buckets, BS_THREADS, 0, stream>>>(bstart, staged, N, row_start, srcs, escp, selfesc);

  // ---- layer 1: 128 -> 4x8, concat, edge scores ----
  gemm_tiled<128><<<cdiv(N, 128), B, 0, stream>>>(x, W1, xh, N);
  gather_kernel<0,true><<<cdiv(N, 4), B, 0, stream>>>(row_start, srcs, escp, selfesc, xh, avecs,
                                                      b1, h1, N, nullptr, nullptr);

  // ---- layer 2: 32 -> 4x8, mean heads; fused layer-3 transform ----
  gemm_tiled<32><<<cdiv(N, 128), B, 0, stream>>>(h1, W2, xh, N);
  gather_kernel<1,false><<<cdiv(N, 4), B, 0, stream>>>(row_start, srcs, escp, selfesc, xh, avecs + 64,
                                                       b2, nullptr, N, W3, xh3);

  // ---- layer 3: 8 -> 4x1, mean heads (xh3 table, scores componentwise) ----
  gather_kernel<2,false><<<cdiv(N, 4), B, 0, stream>>>(row_start, srcs, escp, selfesc, xh3, avecs + 128,
                                                       b3, (float*)d_out, N, nullptr, nullptr);
}

// Round 20
// 357.305 us; speedup vs baseline: 1.0588x; 1.0588x over previous
//
#include <hip/hip_runtime.h>
#include <hip/hip_fp16.h>
#include <cmath>

static inline int cdiv(long a, int b){ return (int)((a + b - 1) / b); }

__device__ __forceinline__ float lrelu(float x){ return fmaxf(x, 0.2f * x); }
__device__ __forceinline__ float elu1(float x){ return x > 0.f ? x : expm1f(x); }
__device__ __forceinline__ float fexp2(float x){ return exp2f(x); }   // v_exp_f32
__device__ __forceinline__ float sel4(float4 v, int h){
  float ab = (h & 1) ? v.y : v.x;
  float cd = (h & 1) ? v.w : v.z;
  return (h & 2) ? cd : ab;
}
__device__ __forceinline__ float dot8(float4 a, float4 b, float4 u, float4 v){
  float p = a.x * u.x;
  p = fmaf(a.y, u.y, p); p = fmaf(a.z, u.z, p); p = fmaf(a.w, u.w, p);
  p = fmaf(b.x, v.x, p); p = fmaf(b.y, v.y, p); p = fmaf(b.z, v.z, p);
  return fmaf(b.w, v.w, p);
}

// 1024-thread block exclusive scan, 2 barriers (wave shfl + 16 wave totals).
__device__ __forceinline__ int block_exscan_1024(int v, int* s_wsum, int t){
  int lane = t & 63, w = t >> 6;
  int x = v;
  #pragma unroll
  for (int off = 1; off < 64; off <<= 1){
    int u = __shfl_up(x, off, 64);
    if (lane >= off) x += u;
  }
  if (lane == 63) s_wsum[w] = x;
  __syncthreads();
  if (w == 0 && lane < 16){
    int y = s_wsum[lane];
    #pragma unroll
    for (int off = 1; off < 16; off <<= 1){
      int u = __shfl_up(y, off, 64);
      if (lane >= off) y += u;
    }
    s_wsum[lane] = y;
  }
  __syncthreads();
  int wbase = w ? s_wsum[w - 1] : 0;
  return wbase + x - v;
}

#define W_SHIFT 7                 // 128 nodes per bucket
#define BUCKET_N (1 << W_SHIFT)
#define NBMAX   1024              // >= number of buckets (782)
#define NCHUNKS 1024              // chunks; also col_scan thread count
#define CH_MAX  3136              // max edges per chunk (E/NCHUNKS = 3125)
#define MS_THREADS 1024

// staged record: {src, dst(full), esc01(fp16x2), esc23(fp16x2)}; esc pre-scaled by log2e

// ---------------- CSR build (atomic-free scheduling) ----------------

__global__ __launch_bounds__(MS_THREADS)
void hist_chunks_kernel(const int* __restrict__ ei, int E, int CH, int* __restrict__ hist2d){
  __shared__ int s_b[NBMAX];
  int t = threadIdx.x, chunk = blockIdx.x;
  s_b[t] = 0;
  __syncthreads();
  int lo = chunk * CH, hi = min(lo + CH, E);
  for (int e = lo + t; e < hi; e += MS_THREADS)
    atomicAdd(&s_b[ei[E + e] >> W_SHIFT], 1);
  __syncthreads();
  hist2d[(size_t)chunk * NBMAX + t] = s_b[t];
}

// per bucket: exclusive prefix over chunks (in place), total -> bcnt
__global__ __launch_bounds__(NCHUNKS)
void col_scan_kernel(int* __restrict__ hist2d, int* __restrict__ bcnt){
  __shared__ int s_wsum[16];
  int b = blockIdx.x, t = threadIdx.x;
  int v = hist2d[(size_t)t * NBMAX + b];
  int excl = block_exscan_1024(v, s_wsum, t);
  hist2d[(size_t)t * NBMAX + b] = excl;
  if (t == 0) bcnt[b] = s_wsum[15];
}

__global__ __launch_bounds__(1024)
void scan_buckets_kernel(const int* __restrict__ bcnt, int nb, int total,
                         int* __restrict__ bstart, int* __restrict__ row_start, int n){
  __shared__ int s_wsum[16];
  int t = threadIdx.x;
  int v = (t < nb) ? bcnt[t] : 0;
  int excl = block_exscan_1024(v, s_wsum, t);
  bstart[t] = excl;                       // for t >= nb, excl == total
  if (t == 0){ bstart[NBMAX] = total; row_start[n] = total; }
}

// wev scaled by log2e; avecs = scaled attention vecs:
// [as1s 0..31 | ad1s 32..63 | as2s 64..95 | ad2s 96..127 | as3s 128..131 | ad3s 132..135]
__global__ void prep_kernel(const float* __restrict__ We, const float* __restrict__ ae,
                            const float* __restrict__ as1, const float* __restrict__ ad1,
                            const float* __restrict__ as2, const float* __restrict__ ad2,
                            const float* __restrict__ as3, const float* __restrict__ ad3,
                            float* __restrict__ wev, float* __restrict__ avecs){
  const float L2E = 1.4426950408889634f;
  int i = threadIdx.x;
  if (i < 32){
    int d = i >> 2, h = i & 3;
    float acc = 0.f;
    #pragma unroll
    for (int c = 0; c < 8; ++c) acc = fmaf(We[d * 32 + h * 8 + c], ae[h * 8 + c], acc);
    wev[d * 4 + h] = acc * L2E;
    avecs[i]      = as1[i] * L2E;
    avecs[32 + i] = ad1[i] * L2E;
    avecs[64 + i] = as2[i] * L2E;
    avecs[96 + i] = ad2[i] * L2E;
  }
  if (i < 4){
    avecs[128 + i] = as3[i] * L2E;
    avecs[132 + i] = ad3[i] * L2E;
  }
}

// multisplit v2: sort the whole chunk by bucket in LDS, then copy out densely.
__global__ __launch_bounds__(MS_THREADS)
void multisplit_kernel(const int* __restrict__ ei, int E, int CH,
                       const float* __restrict__ eattr, const float* __restrict__ wev,
                       const int* __restrict__ bstart, const int* __restrict__ prefix2d,
                       int4* __restrict__ staged){
  __shared__ int4 s_rec[CH_MAX];        // 50.2 KB
  __shared__ int s_fill[NBMAX];
  __shared__ int s_lbase[NBMAX];
  __shared__ int s_shift[NBMAX];
  __shared__ float s_wev[32];
  __shared__ int s_wsum[16];
  int t = threadIdx.x, chunk = blockIdx.x;
  if (t < 32) s_wev[t] = wev[t];
  s_fill[t] = 0;
  __syncthreads();
  int lo = chunk * CH, hi = min(lo + CH, E);
  int cnt = hi - lo;
  for (int e = lo + t; e < hi; e += MS_THREADS)
    atomicAdd(&s_fill[ei[E + e] >> W_SHIFT], 1);
  __syncthreads();
  int v = s_fill[t];
  int excl = block_exscan_1024(v, s_wsum, t);
  s_lbase[t] = excl;
  s_shift[t] = bstart[t] + prefix2d[(size_t)chunk * NBMAX + t] - excl;
  s_fill[t] = 0;
  __syncthreads();
  for (int e = lo + t; e < hi; e += MS_THREADS){
    int d = ei[E + e];
    int b = d >> W_SHIFT;
    const float4* ea = (const float4*)(eattr + (size_t)e * 8);
    float4 v0 = ea[0], v1 = ea[1];
    float av[8] = {v0.x, v0.y, v0.z, v0.w, v1.x, v1.y, v1.z, v1.w};
    float e0 = 0, e1 = 0, e2 = 0, e3 = 0;
    #pragma unroll
    for (int k = 0; k < 8; ++k){
      e0 = fmaf(av[k], s_wev[k * 4 + 0], e0);
      e1 = fmaf(av[k], s_wev[k * 4 + 1], e1);
      e2 = fmaf(av[k], s_wev[k * 4 + 2], e2);
      e3 = fmaf(av[k], s_wev[k * 4 + 3], e3);
    }
    __half2 h01 = __floats2half2_rn(e0, e1);
    __half2 h23 = __floats2half2_rn(e2, e3);
    int pos = s_lbase[b] + atomicAdd(&s_fill[b], 1);
    s_rec[pos] = make_int4(ei[e], d,
                           __builtin_bit_cast(int, h01), __builtin_bit_cast(int, h23));
  }
  __syncthreads();
  // dense copy-out: consecutive threads -> mostly-consecutive global addresses
  for (int i = t; i < cnt; i += MS_THREADS){
    int4 r = s_rec[i];
    staged[s_shift[r.y >> W_SHIFT] + i] = r;
  }
}

// per-bucket: counts -> row_start; permute staged to final CSR (srcs 4B + escp 8B);
// then 8-lane-per-node esc row sums from the L2-hot escp window -> selfesc.
__global__ __launch_bounds__(MS_THREADS)
void bucket_scatter_kernel(const int* __restrict__ bstart, const int4* __restrict__ staged,
                           int n, int* __restrict__ row_start, int* __restrict__ srcs,
                           uint2* __restrict__ escp, float4* __restrict__ selfesc){
  __shared__ int s_cnt[BUCKET_N];
  __shared__ int s_cur[BUCKET_N];
  __shared__ int s_start[BUCKET_N];
  __shared__ int s_wsum[2];
  int b = blockIdx.x, t = threadIdx.x;
  int node0 = b << W_SHIFT;
  if (t < BUCKET_N) s_cnt[t] = 0;
  __syncthreads();
  int lo = bstart[b], hi = bstart[b + 1];
  for (int i = lo + t; i < hi; i += MS_THREADS)
    atomicAdd(&s_cnt[staged[i].y & (BUCKET_N - 1)], 1);
  __syncthreads();
  int lane = t & 63, w = t >> 6;
  if (w < 2){
    int v = s_cnt[t];
    int x = v;
    #pragma unroll
    for (int off = 1; off < 64; off <<= 1){
      int u = __shfl_up(x, off, 64);
      if (lane >= off) x += u;
    }
    if (lane == 63) s_wsum[w] = x;
    s_cur[t] = x - v;
  }
  __syncthreads();
  if (t < BUCKET_N){
    int excl = s_cur[t] + (w ? s_wsum[0] : 0);
    int nd = node0 + t;
    if (nd <= n) row_start[nd] = lo + excl;
    s_start[t] = lo + excl;
    s_cur[t] = lo + excl;
  }
  __syncthreads();
  for (int i = lo + t; i < hi; i += MS_THREADS){
    int4 r = staged[i];
    int pos = atomicAdd(&s_cur[r.y & (BUCKET_N - 1)], 1);
    srcs[pos] = r.x;
    escp[pos] = make_uint2((unsigned)r.z, (unsigned)r.w);
  }
  __syncthreads();
  int nl = t >> 3, sub = t & 7;
  int nd2 = node0 + nl;
  if (nd2 >= n) return;
  int r0 = s_start[nl], r1 = s_start[nl] + s_cnt[nl];
  float e0 = 0, e1 = 0, e2 = 0, e3 = 0;
  for (int k = r0 + sub; k < r1; k += 8){
    uint2 u = escp[k];
    float2 f01 = __half22float2(__builtin_bit_cast(__half2, u.x));
    float2 f23 = __half22float2(__builtin_bit_cast(__half2, u.y));
    e0 += f01.x; e1 += f01.y; e2 += f23.x; e3 += f23.y;
  }
  #pragma unroll
  for (int off = 1; off < 8; off <<= 1){
    e0 += __shfl_xor(e0, off, 64); e1 += __shfl_xor(e1, off, 64);
    e2 += __shfl_xor(e2, off, 64); e3 += __shfl_xor(e3, off, 64);
  }
  if (sub == 0){
    float inv = 1.f / fmaxf((float)s_cnt[nl], 1.f);
    selfesc[nd2] = make_float4(e0 * inv, e1 * inv, e2 * inv, e3 * inv);
  }
}

// ---------------- register-tiled node transform (pure GEMM) ----------------
template<int K>
__global__ __launch_bounds__(256)
void gemm_tiled(const float* __restrict__ A, const float* __restrict__ W,
                float* __restrict__ out, int n){
  constexpr int KH = (K > 64) ? 64 : K;
  constexpr int K4 = KH / 4;
  __shared__ float s_AT[KH * 128];
  __shared__ float s_W[K * 32];
  int t = threadIdx.x;
  for (int i = t; i < K * 32; i += 256) s_W[i] = W[i];
  int n0 = blockIdx.x * 128;
  int nrows = min(128, n - n0);
  int rg = t >> 3, q = t & 7;
  float4 acc[4] = {{0,0,0,0},{0,0,0,0},{0,0,0,0},{0,0,0,0}};

  for (int k0 = 0; k0 < K; k0 += KH){
    __syncthreads();
    #pragma unroll
    for (int it = 0; it < 128 * K4 / 256; ++it){
      int idx = t + it * 256;
      int row = idx & 127, k4 = idx >> 7;
      if (row < nrows){
        float4 v = *(const float4*)(A + (size_t)(n0 + row) * K + k0 + 4 * k4);
        s_AT[(4 * k4 + 0) * 128 + row] = v.x;
        s_AT[(4 * k4 + 1) * 128 + row] = v.y;
        s_AT[(4 * k4 + 2) * 128 + row] = v.z;
        s_AT[(4 * k4 + 3) * 128 + row] = v.w;
      }
    }
    __syncthreads();
    #pragma unroll 4
    for (int k = 0; k < KH; ++k){
      float4 a4 = *(const float4*)(s_AT + k * 128 + 4 * rg);
      float4 w4 = *(const float4*)(s_W + (k0 + k) * 32 + 4 * q);
      acc[0].x = fmaf(a4.x, w4.x, acc[0].x); acc[0].y = fmaf(a4.x, w4.y, acc[0].y);
      acc[0].z = fmaf(a4.x, w4.z, acc[0].z); acc[0].w = fmaf(a4.x, w4.w, acc[0].w);
      acc[1].x = fmaf(a4.y, w4.x, acc[1].x); acc[1].y = fmaf(a4.y, w4.y, acc[1].y);
      acc[1].z = fmaf(a4.y, w4.z, acc[1].z); acc[1].w = fmaf(a4.y, w4.w, acc[1].w);
      acc[2].x = fmaf(a4.z, w4.x, acc[2].x); acc[2].y = fmaf(a4.z, w4.y, acc[2].y);
      acc[2].z = fmaf(a4.z, w4.z, acc[2].z); acc[2].w = fmaf(a4.z, w4.w, acc[2].w);
      acc[3].x = fmaf(a4.w, w4.x, acc[3].x); acc[3].y = fmaf(a4.w, w4.y, acc[3].y);
      acc[3].z = fmaf(a4.w, w4.z, acc[3].z); acc[3].w = fmaf(a4.w, w4.w, acc[3].w);
    }
  }
  #pragma unroll
  for (int i = 0; i < 4; ++i){
    int row = n0 + 4 * rg + i;
    if ((4 * rg + i) < nrows) ((float4*)out)[(size_t)row * 8 + q] = acc[i];
  }
}

// ---------------- one-phase CSR gather: 4 lanes/edge, srcs/escp prefetch ----------------
template<int MODE, bool EDGE>
__global__ void gather_kernel(const int* __restrict__ row_start, const int* __restrict__ srcs,
                              const uint2* __restrict__ escp, const float4* __restrict__ selfesc,
                              const float* __restrict__ xh, const float* __restrict__ avq,
                              const float* __restrict__ bias, float* __restrict__ out, int n,
                              const float* __restrict__ W3p, float* __restrict__ xh3){
  int wv = threadIdx.x >> 6, lane = threadIdx.x & 63;
  int node = blockIdx.x * 4 + wv;

  if constexpr (MODE == 2){
    if (node >= n) return;
    int rs = row_start[node], deg = row_start[node + 1] - rs;
    float4 a3s = *(const float4*)avq;
    float4 a3d = *(const float4*)(avq + 4);
    float4 xvn = ((const float4*)xh)[node];
    float4 sdn = {xvn.x * a3d.x, xvn.y * a3d.y, xvn.z * a3d.z, xvn.w * a3d.w};
    float4 acc = {0,0,0,0}, dsum = {0,0,0,0};
    for (int k = lane; k < deg; k += 64){
      int s = srcs[rs + k];
      float4 xv = ((const float4*)xh)[s];
      float4 w;
      w.x = fexp2(lrelu(fmaf(xv.x, a3s.x, sdn.x)));
      w.y = fexp2(lrelu(fmaf(xv.y, a3s.y, sdn.y)));
      w.z = fexp2(lrelu(fmaf(xv.z, a3s.z, sdn.z)));
      w.w = fexp2(lrelu(fmaf(xv.w, a3s.w, sdn.w)));
      dsum.x += w.x; dsum.y += w.y; dsum.z += w.z; dsum.w += w.w;
      acc.x = fmaf(w.x, xv.x, acc.x); acc.y = fmaf(w.y, xv.y, acc.y);
      acc.z = fmaf(w.z, xv.z, acc.z); acc.w = fmaf(w.w, xv.w, acc.w);
    }
    #pragma unroll
    for (int off = 1; off < 64; off <<= 1){
      acc.x += __shfl_xor(acc.x, off, 64); acc.y += __shfl_xor(acc.y, off, 64);
      acc.z += __shfl_xor(acc.z, off, 64); acc.w += __shfl_xor(acc.w, off, 64);
      dsum.x += __shfl_xor(dsum.x, off, 64); dsum.y += __shfl_xor(dsum.y, off, 64);
      dsum.z += __shfl_xor(dsum.z, off, 64); dsum.w += __shfl_xor(dsum.w, off, 64);
    }
    if (lane == 0){
      float4 wsf;
      wsf.x = fexp2(lrelu(fmaf(xvn.x, a3s.x, sdn.x)));
      wsf.y = fexp2(lrelu(fmaf(xvn.y, a3s.y, sdn.y)));
      wsf.z = fexp2(lrelu(fmaf(xvn.z, a3s.z, sdn.z)));
      wsf.w = fexp2(lrelu(fmaf(xvn.w, a3s.w, sdn.w)));
      float v = (acc.x + wsf.x * xvn.x) / (dsum.x + wsf.x + 1e-16f)
              + (acc.y + wsf.y * xvn.y) / (dsum.y + wsf.y + 1e-16f)
              + (acc.z + wsf.z * xvn.z) / (dsum.z + wsf.z + 1e-16f)
              + (acc.w + wsf.w * xvn.w) / (dsum.w + wsf.w + 1e-16f);
      out[node] = 0.25f * v + bias[0];
    }
    return;
  } else {
  __shared__ float s_w3[32];
  if constexpr (MODE == 1){
    if (threadIdx.x < 32) s_w3[threadIdx.x] = W3p[threadIdx.x];
    __syncthreads();
  }
  if (node >= n) return;
  int rs = row_start[node], deg = row_start[node + 1] - rs;
  int h = lane & 3, sg = lane >> 2;          // head, edge slot (16 edges/iter)
  const float4* xh4 = (const float4*)xh;
  float4 as0 = ((const float4*)avq)[2 * h];
  float4 as1v = ((const float4*)avq)[2 * h + 1];
  float4 ad0 = ((const float4*)(avq + 32))[2 * h];
  float4 ad1v = ((const float4*)(avq + 32))[2 * h + 1];
  float4 xn0 = xh4[(size_t)node * 8 + 2 * h];
  float4 xn1 = xh4[(size_t)node * 8 + 2 * h + 1];
  float sdh = dot8(xn0, xn1, ad0, ad1v);
  float4 acc0 = {0,0,0,0}, acc1 = {0,0,0,0};
  float dacc = 0.f;
  const int* sp = srcs + rs;

  int k = sg;
  int s_cur = (k < deg) ? sp[k] : -1;
  uint2 u_cur = (EDGE && k < deg) ? escp[rs + k] : make_uint2(0u, 0u);
  for (int base = 0; base < deg; base += 16){
    int k2 = base + 16 + sg;
    int s_nxt = (k2 < deg) ? sp[k2] : -1;
    uint2 u_nxt = (EDGE && k2 < deg) ? escp[rs + k2] : make_uint2(0u, 0u);
    if (s_cur >= 0){
      float4 xv0 = xh4[(size_t)s_cur * 8 + 2 * h];
      float4 xv1 = xh4[(size_t)s_cur * 8 + 2 * h + 1];
      float a = dot8(xv0, xv1, as0, as1v) + sdh;
      if constexpr (EDGE){
        float2 f01 = __half22float2(__builtin_bit_cast(__half2, u_cur.x));
        float2 f23 = __half22float2(__builtin_bit_cast(__half2, u_cur.y));
        a += (h == 0) ? f01.x : (h == 1) ? f01.y : (h == 2) ? f23.x : f23.y;
      }
      float w = fexp2(lrelu(a));
      dacc += w;
      acc0.x = fmaf(w, xv0.x, acc0.x); acc0.y = fmaf(w, xv0.y, acc0.y);
      acc0.z = fmaf(w, xv0.z, acc0.z); acc0.w = fmaf(w, xv0.w, acc0.w);
      acc1.x = fmaf(w, xv1.x, acc1.x); acc1.y = fmaf(w, xv1.y, acc1.y);
      acc1.z = fmaf(w, xv1.z, acc1.z); acc1.w = fmaf(w, xv1.w, acc1.w);
    }
    s_cur = s_nxt;
    u_cur = u_nxt;
  }

  #pragma unroll
  for (int off = 4; off < 64; off <<= 1){
    acc0.x += __shfl_xor(acc0.x, off, 64); acc0.y += __shfl_xor(acc0.y, off, 64);
    acc0.z += __shfl_xor(acc0.z, off, 64); acc0.w += __shfl_xor(acc0.w, off, 64);
    acc1.x += __shfl_xor(acc1.x, off, 64); acc1.y += __shfl_xor(acc1.y, off, 64);
    acc1.z += __shfl_xor(acc1.z, off, 64); acc1.w += __shfl_xor(acc1.w, off, 64);
    dacc   += __shfl_xor(dacc,   off, 64);
  }
  float a_self = dot8(xn0, xn1, as0, as1v) + sdh;
  if constexpr (EDGE) a_self += sel4(selfesc[node], h);
  float wsel = fexp2(lrelu(a_self));
  acc0.x = fmaf(wsel, xn0.x, acc0.x); acc0.y = fmaf(wsel, xn0.y, acc0.y);
  acc0.z = fmaf(wsel, xn0.z, acc0.z); acc0.w = fmaf(wsel, xn0.w, acc0.w);
  acc1.x = fmaf(wsel, xn1.x, acc1.x); acc1.y = fmaf(wsel, xn1.y, acc1.y);
  acc1.z = fmaf(wsel, xn1.z, acc1.z); acc1.w = fmaf(wsel, xn1.w, acc1.w);
  dacc += wsel;
  float rin = 1.f / (dacc + 1e-16f);
  float4 v0 = {acc0.x * rin, acc0.y * rin, acc0.z * rin, acc0.w * rin};
  float4 v1 = {acc1.x * rin, acc1.y * rin, acc1.z * rin, acc1.w * rin};

  if constexpr (MODE == 0){
    if (sg == 0){
      float4 ba = ((const float4*)bias)[2 * h];
      float4 bb = ((const float4*)bias)[2 * h + 1];
      v0.x = elu1(v0.x + ba.x); v0.y = elu1(v0.y + ba.y);
      v0.z = elu1(v0.z + ba.z); v0.w = elu1(v0.w + ba.w);
      v1.x = elu1(v1.x + bb.x); v1.y = elu1(v1.y + bb.y);
      v1.z = elu1(v1.z + bb.z); v1.w = elu1(v1.w + bb.w);
      ((float4*)out)[(size_t)node * 8 + 2 * h] = v0;
      ((float4*)out)[(size_t)node * 8 + 2 * h + 1] = v1;
    }
  } else {
    #pragma unroll
    for (int off = 1; off < 4; off <<= 1){
      v0.x += __shfl_xor(v0.x, off, 64); v0.y += __shfl_xor(v0.y, off, 64);
      v0.z += __shfl_xor(v0.z, off, 64); v0.w += __shfl_xor(v0.w, off, 64);
      v1.x += __shfl_xor(v1.x, off, 64); v1.y += __shfl_xor(v1.y, off, 64);
      v1.z += __shfl_xor(v1.z, off, 64); v1.w += __shfl_xor(v1.w, off, 64);
    }
    float4 ba = ((const float4*)bias)[0];
    float4 bb = ((const float4*)bias)[1];
    float h2v[8];
    h2v[0] = elu1(v0.x * 0.25f + ba.x); h2v[1] = elu1(v0.y * 0.25f + ba.y);
    h2v[2] = elu1(v0.z * 0.25f + ba.z); h2v[3] = elu1(v0.w * 0.25f + ba.w);
    h2v[4] = elu1(v1.x * 0.25f + bb.x); h2v[5] = elu1(v1.y * 0.25f + bb.y);
    h2v[6] = elu1(v1.z * 0.25f + bb.z); h2v[7] = elu1(v1.w * 0.25f + bb.w);
    if (sg == 0){
      float a = 0.f;
      #pragma unroll
      for (int kk = 0; kk < 8; ++kk) a = fmaf(h2v[kk], s_w3[kk * 4 + h], a);
      xh3[(size_t)node * 4 + h] = a;
    }
  }
  }
}

// ---------------- launcher ----------------

extern "C" void kernel_launch(void* const* d_in, const int* in_sizes, int n_in,
                              void* d_out, int out_size, void* d_ws, size_t ws_size,
                              hipStream_t stream){
  const float* x     = (const float*)d_in[0];
  const float* eattr = (const float*)d_in[1];
  const int*   ei    = (const int*)d_in[2];
  const float* W1  = (const float*)d_in[3];
  const float* as1 = (const float*)d_in[4];
  const float* ad1 = (const float*)d_in[5];
  const float* We1 = (const float*)d_in[6];
  const float* ae1 = (const float*)d_in[7];
  const float* b1  = (const float*)d_in[8];
  const float* W2  = (const float*)d_in[9];
  const float* as2 = (const float*)d_in[10];
  const float* ad2 = (const float*)d_in[11];
  const float* b2  = (const float*)d_in[12];
  const float* W3  = (const float*)d_in[13];
  const float* as3 = (const float*)d_in[14];
  const float* ad3 = (const float*)d_in[15];
  const float* b3  = (const float*)d_in[16];

  const int N = in_sizes[0] / 128;
  const int E = in_sizes[2] / 2;
  const int nb_buckets = (N + BUCKET_N - 1) >> W_SHIFT;   // 782 for N=100000
  const int CH = cdiv(E, NCHUNKS);                        // 3125 (<= CH_MAX)

  char* b0 = (char*)d_ws;
  int4* staged = (int4*)b0;                 // E*16; aliased by xh/h1 after CSR build
  float* fp = (float*)b0;
  float* xh = fp; fp += (size_t)N * 32;
  float* h1 = fp; fp += (size_t)N * 32;
  int*  srcs = (int*)(b0 + (size_t)E * 16);
  uint2* escp = (uint2*)(b0 + (size_t)E * 20);
  int* hist2d = (int*)(b0 + (size_t)E * 28);
  float4* selfesc = (float4*)(hist2d + (size_t)NCHUNKS * NBMAX);
  float* xh3 = (float*)(selfesc + N);
  int* ip = (int*)(xh3 + (size_t)N * 4);
  int* bcnt      = ip; ip += NBMAX;
  int* bstart    = ip; ip += NBMAX + 1;
  int* row_start = ip; ip += N + 1;
  float* wev   = (float*)ip;
  float* avecs = wev + 32;

  const int B = 256;

  // ---- CSR build: plan (no global atomics) -> LDS record-sort multisplit -> bucket scatter ----
  prep_kernel<<<1, 64, 0, stream>>>(We1, ae1, as1, ad1, as2, ad2, as3, ad3, wev, avecs);
  hist_chunks_kernel<<<NCHUNKS, MS_THREADS, 0, stream>>>(ei, E, CH, hist2d);
  col_scan_kernel<<<nb_buckets, NCHUNKS, 0, stream>>>(hist2d, bcnt);
  scan_buckets_kernel<<<1, 1024, 0, stream>>>(bcnt, nb_buckets, E, bstart, row_start, N);
  multisplit_kernel<<<NCHUNKS, MS_THREADS, 0, stream>>>(ei, E, CH, eattr, wev, bstart, hist2d, staged);
  bucket_scatter_kernel<<<nb_buckets, MS_THREADS, 0, stream>>>(bstart, staged, N, row_start, srcs, escp, selfesc);

  // ---- layer 1: 128 -> 4x8, concat, edge scores ----
  gemm_tiled<128><<<cdiv(N, 128), B, 0, stream>>>(x, W1, xh, N);
  gather_kernel<0,true><<<cdiv(N, 4), B, 0, stream>>>(row_start, srcs, escp, selfesc, xh, avecs,
                                                      b1, h1, N, nullptr, nullptr);

  // ---- layer 2: 32 -> 4x8, mean heads; fused layer-3 transform ----
  gemm_tiled<32><<<cdiv(N, 128), B, 0, stream>>>(h1, W2, xh, N);
  gather_kernel<1,false><<<cdiv(N, 4), B, 0, stream>>>(row_start, srcs, escp, selfesc, xh, avecs + 64,
                                                       b2, nullptr, N, W3, xh3);

  // ---- layer 3: 8 -> 4x1, mean heads (xh3 table, scores componentwise) ----
  gather_kernel<2,false><<<cdiv(N, 4), B, 0, stream>>>(row_start, srcs, escp, selfesc, xh3, avecs + 128,
                                                       b3, (float*)d_out, N, nullptr, nullptr);
}